// Round 8
// baseline (2447.617 us; speedup 1.0000x reference)
//
#include <hip/hip_runtime.h>
#include <cmath>

// Problem constants (fixed by reference file)
#define B_     8
#define NH_    32
#define HD_    128
#define HID_   4096
#define MAXS_  4096
#define NPAIR_ (B_ * NH_)          // 256 (b,h) pairs
#define NSPLIT_ 4                  // key-splits per pair
#define PSTR_  132                 // partial stride: m, l, pad, pad, acc[128]
#define NEG_BIG_ (-1e30f)

typedef float f4_ __attribute__((ext_vector_type(4)));

__device__ __forceinline__ f4_ ntload4(const float* p) {
  return __builtin_nontemporal_load((const f4_*)p);
}
__device__ __forceinline__ f4_ ld4(const float* p) {
  return *(const f4_*)p;
}
__device__ __forceinline__ float dot4(f4_ a, f4_ b) {
  f4_ m = a * b;
  return m.x + m.y + m.z + m.w;
}

// ===================== real pipeline (round-5 config, 198us) ==============

// out[b][row] = sum_j W[row][j] * x[b][j]  for W in {W0,W1,W2} by blockIdx>>9.
// 8 rows/block (2 rows/wave). Weights NORMAL loads (L3-resident across graph
// replays; nt KV stream cannot evict them). x served from L2.
__global__ __launch_bounds__(256) void gemv_rows(
    const float* __restrict__ W0, const float* __restrict__ W1,
    const float* __restrict__ W2, const float* __restrict__ x,
    float* __restrict__ out)
{
  const int bid = blockIdx.x;
  const int m   = bid >> 9;               // matrix index (0..2)
  const int rb  = (bid & 511) << 3;       // first of 8 rows
  const float* __restrict__ W = (m == 0) ? W0 : ((m == 1) ? W1 : W2);
  float* o = out + m * (B_ * HID_);

  const int wib  = threadIdx.x >> 6;
  const int lane = threadIdx.x & 63;
  const int r0   = rb + wib * 2;

  float acc[2][8];
#pragma unroll
  for (int r = 0; r < 2; ++r)
#pragma unroll
    for (int b = 0; b < 8; ++b) acc[r][b] = 0.f;

  const float* Wp = W + (size_t)r0 * HID_ + lane * 4;
#pragma unroll 2
  for (int u = 0; u < 16; ++u) {
    const int j = u * 256;
    f4_ w0 = ld4(Wp + j);
    f4_ w1 = ld4(Wp + j + HID_);
#pragma unroll
    for (int b = 0; b < 8; ++b) {
      f4_ xb = ld4(x + b * HID_ + j + lane * 4);
      acc[0][b] += dot4(w0, xb);
      acc[1][b] += dot4(w1, xb);
    }
  }

#pragma unroll
  for (int r = 0; r < 2; ++r)
#pragma unroll
    for (int b = 0; b < 8; ++b) {
      float v = acc[r][b];
#pragma unroll
      for (int off = 32; off; off >>= 1) v += __shfl_xor(v, off);
      acc[r][b] = v;
    }

  if (lane == 0) {
#pragma unroll
    for (int r = 0; r < 2; ++r)
#pragma unroll
      for (int b = 0; b < 8; ++b)
        o[(size_t)b * HID_ + r0 + r] = acc[r][b];
  }
}

// Flash-decoding partials: 4 blocks (256 thr = 4 waves) per (b,h) pair.
// K/V rows nt (stream-once; must not evict L3-resident weights).
__global__ __launch_bounds__(256, 4) void attn_partial(
    const float* __restrict__ qkv, const float* __restrict__ ck,
    const float* __restrict__ cv, const int* __restrict__ ppos,
    float* __restrict__ part)
{
  __shared__ float sm[4], sl[4];
  __shared__ float sacc[4][HD_];

  const int pos  = *ppos;
  const int bid  = blockIdx.x;
  const int pair = bid >> 2;
  const int s    = bid & (NSPLIT_ - 1);
  const int b    = pair >> 5;
  const int h    = pair & (NH_ - 1);
  const int w    = threadIdx.x >> 6;
  const int lane = threadIdx.x & 63;
  const int half = lane >> 5, l32 = lane & 31;
  const int k0   = s * 512 + w * 128;

  float m = NEG_BIG_, l = 0.f;
  f4_ acc = (f4_)0.f;

  if (k0 <= pos) {
    const float scale = 0.08838834764831845f;   // 1/sqrt(128)
    f4_ q4 = ld4(qkv + b * HID_ + h * HD_ + l32 * 4) * scale;
    const float* kfresh = qkv + B_ * HID_     + b * HID_ + h * HD_;
    const float* vfresh = qkv + 2 * B_ * HID_ + b * HID_ + h * HD_;
    const float* ckh = ck + ((size_t)(b * NH_ + h)) * MAXS_ * HD_;
    const float* cvh = cv + ((size_t)(b * NH_ + h)) * MAXS_ * HD_;

    for (int c = 0; c < 8; ++c) {
      const int kbase = k0 + c * 16;
      f4_ k4[8], v4[8];
#pragma unroll
      for (int j = 0; j < 8; ++j) {
        const int ki = kbase + 2 * j + half;
        const float* kp = (ki == pos) ? kfresh : (ckh + (size_t)ki * HD_);
        const float* vp = (ki == pos) ? vfresh : (cvh + (size_t)ki * HD_);
        k4[j] = ntload4(kp + l32 * 4);
        v4[j] = ntload4(vp + l32 * 4);
      }

      float sc[8];
#pragma unroll
      for (int j = 0; j < 8; ++j) sc[j] = dot4(q4, k4[j]);

#pragma unroll
      for (int off = 16; off >= 1; off >>= 1)
#pragma unroll
        for (int j = 0; j < 8; ++j) sc[j] += __shfl_xor(sc[j], off);

#pragma unroll
      for (int j = 0; j < 8; ++j) {
        const int ki = kbase + 2 * j + half;
        if (ki > pos) sc[j] = -INFINITY;
      }

      const float cm = fmaxf(fmaxf(fmaxf(sc[0], sc[1]), fmaxf(sc[2], sc[3])),
                             fmaxf(fmaxf(sc[4], sc[5]), fmaxf(sc[6], sc[7])));
      const float mn   = fmaxf(m, cm);
      const float corr = __expf(m - mn);
      float p[8], ps = 0.f;
#pragma unroll
      for (int j = 0; j < 8; ++j) { p[j] = __expf(sc[j] - mn); ps += p[j]; }
      l = l * corr + ps;
      acc *= corr;
#pragma unroll
      for (int j = 0; j < 8; ++j) acc += p[j] * v4[j];
      m = mn;
    }
  }

  const float mo = __shfl_xor(m, 32);
  const float lo = __shfl_xor(l, 32);
  f4_ ao;
  ao.x = __shfl_xor(acc.x, 32); ao.y = __shfl_xor(acc.y, 32);
  ao.z = __shfl_xor(acc.z, 32); ao.w = __shfl_xor(acc.w, 32);
  const float mm = fmaxf(m, mo);
  const float w0 = __expf(m - mm), w1 = __expf(mo - mm);
  const float lm = l * w0 + lo * w1;
  f4_ am = acc * w0 + ao * w1;

  if (half == 0) {
    *(f4_*)&sacc[w][l32 * 4] = am;
    if (l32 == 0) { sm[w] = mm; sl[w] = lm; }
  }
  __syncthreads();

  if (threadIdx.x < 32) {
    const int t = threadIdx.x;
    float mg = NEG_BIG_;
#pragma unroll
    for (int u = 0; u < 4; ++u)
      if (sl[u] > 0.f) mg = fmaxf(mg, sm[u]);
    float ls = 0.f;
    f4_ o = (f4_)0.f;
#pragma unroll
    for (int u = 0; u < 4; ++u)
      if (sl[u] > 0.f) {
        const float wu = __expf(sm[u] - mg);
        ls += sl[u] * wu;
        o  += wu * ld4(&sacc[u][t * 4]);
      }
    float* pb = part + (size_t)bid * PSTR_;
    *(f4_*)(pb + 4 + t * 4) = o;
    if (t == 0) { pb[0] = (ls > 0.f) ? mg : NEG_BIG_; pb[1] = ls; }
  }
}

// Merge the 4 split partials per (b,h) into attn output [b][h*128+d].
__global__ __launch_bounds__(128) void attn_combine(
    const float* __restrict__ part, float* __restrict__ attnout)
{
  const int pair = blockIdx.x;
  const int d    = threadIdx.x;
  const float* pb = part + (size_t)pair * NSPLIT_ * PSTR_;

  float mg = NEG_BIG_;
#pragma unroll
  for (int u = 0; u < NSPLIT_; ++u) {
    const float lu = pb[u * PSTR_ + 1];
    if (lu > 0.f) mg = fmaxf(mg, pb[u * PSTR_]);
  }
  float ls = 0.f, o = 0.f;
#pragma unroll
  for (int u = 0; u < NSPLIT_; ++u) {
    const float lu = pb[u * PSTR_ + 1];
    if (lu > 0.f) {
      const float wu = __expf(pb[u * PSTR_] - mg);
      ls += lu * wu;
      o  += wu * pb[u * PSTR_ + 4 + d];
    }
  }
  attnout[pair * HD_ + d] = o / ls;
}

// ===================== measurement probes (outputs unused) ================
// Each probe repeats one phase `reps` times so its dispatch exceeds the
// ~315us fill threshold and surfaces in the rocprof top-5 with its own
// dur/FETCH/BW counters. T_phase = dur_probe / reps.

__global__ __launch_bounds__(256) void gemv_probe(
    const float* __restrict__ W0, const float* __restrict__ W1,
    const float* __restrict__ W2, const float* __restrict__ x,
    float* __restrict__ out, int reps, int nb_per_mat)
{
  for (int rep = 0; rep < reps; ++rep) {
    const int bid = blockIdx.x;
    const int m   = bid / nb_per_mat;
    const int rb  = (bid % nb_per_mat) << 3;
    const float* __restrict__ W = (m == 0) ? W0 : ((m == 1) ? W1 : W2);
    float* o = out + m * (B_ * HID_);

    const int wib  = threadIdx.x >> 6;
    const int lane = threadIdx.x & 63;
    const int r0   = rb + wib * 2;

    float acc[2][8];
#pragma unroll
    for (int r = 0; r < 2; ++r)
#pragma unroll
      for (int b = 0; b < 8; ++b) acc[r][b] = 0.f;

    const float* Wp = W + (size_t)r0 * HID_ + lane * 4;
#pragma unroll 2
    for (int u = 0; u < 16; ++u) {
      const int j = u * 256;
      f4_ w0 = ld4(Wp + j);
      f4_ w1 = ld4(Wp + j + HID_);
#pragma unroll
      for (int b = 0; b < 8; ++b) {
        f4_ xb = ld4(x + b * HID_ + j + lane * 4);
        acc[0][b] += dot4(w0, xb);
        acc[1][b] += dot4(w1, xb);
      }
    }

#pragma unroll
    for (int r = 0; r < 2; ++r)
#pragma unroll
      for (int b = 0; b < 8; ++b) {
        float v = acc[r][b];
#pragma unroll
        for (int off = 32; off; off >>= 1) v += __shfl_xor(v, off);
        acc[r][b] = v;
      }

    if (lane == 0) {
#pragma unroll
      for (int r = 0; r < 2; ++r)
#pragma unroll
        for (int b = 0; b < 8; ++b)
          o[(size_t)b * HID_ + r0 + r] = acc[r][b];
    }
  }
}

__global__ __launch_bounds__(256, 4) void attn_probe(
    const float* __restrict__ qkv, const float* __restrict__ ck,
    const float* __restrict__ cv, const int* __restrict__ ppos,
    float* __restrict__ part, int reps)
{
  __shared__ float sm[4], sl[4];
  __shared__ float sacc[4][HD_];

  for (int rep = 0; rep < reps; ++rep) {
    const int pos  = *ppos;
    const int bid  = blockIdx.x;
    const int pair = bid >> 2;
    const int s    = bid & (NSPLIT_ - 1);
    const int b    = pair >> 5;
    const int h    = pair & (NH_ - 1);
    const int w    = threadIdx.x >> 6;
    const int lane = threadIdx.x & 63;
    const int half = lane >> 5, l32 = lane & 31;
    const int k0   = s * 512 + w * 128;

    float m = NEG_BIG_, l = 0.f;
    f4_ acc = (f4_)0.f;

    if (k0 <= pos) {
      const float scale = 0.08838834764831845f;
      f4_ q4 = ld4(qkv + b * HID_ + h * HD_ + l32 * 4) * scale;
      const float* kfresh = qkv + B_ * HID_     + b * HID_ + h * HD_;
      const float* vfresh = qkv + 2 * B_ * HID_ + b * HID_ + h * HD_;
      const float* ckh = ck + ((size_t)(b * NH_ + h)) * MAXS_ * HD_;
      const float* cvh = cv + ((size_t)(b * NH_ + h)) * MAXS_ * HD_;

      for (int c = 0; c < 8; ++c) {
        const int kbase = k0 + c * 16;
        f4_ k4[8], v4[8];
#pragma unroll
        for (int j = 0; j < 8; ++j) {
          const int ki = kbase + 2 * j + half;
          const float* kp = (ki == pos) ? kfresh : (ckh + (size_t)ki * HD_);
          const float* vp = (ki == pos) ? vfresh : (cvh + (size_t)ki * HD_);
          k4[j] = ntload4(kp + l32 * 4);
          v4[j] = ntload4(vp + l32 * 4);
        }

        float sc[8];
#pragma unroll
        for (int j = 0; j < 8; ++j) sc[j] = dot4(q4, k4[j]);

#pragma unroll
        for (int off = 16; off >= 1; off >>= 1)
#pragma unroll
          for (int j = 0; j < 8; ++j) sc[j] += __shfl_xor(sc[j], off);

#pragma unroll
        for (int j = 0; j < 8; ++j) {
          const int ki = kbase + 2 * j + half;
          if (ki > pos) sc[j] = -INFINITY;
        }

        const float cm = fmaxf(fmaxf(fmaxf(sc[0], sc[1]), fmaxf(sc[2], sc[3])),
                               fmaxf(fmaxf(sc[4], sc[5]), fmaxf(sc[6], sc[7])));
        const float mn   = fmaxf(m, cm);
        const float corr = __expf(m - mn);
        float p[8], ps = 0.f;
#pragma unroll
        for (int j = 0; j < 8; ++j) { p[j] = __expf(sc[j] - mn); ps += p[j]; }
        l = l * corr + ps;
        acc *= corr;
#pragma unroll
        for (int j = 0; j < 8; ++j) acc += p[j] * v4[j];
        m = mn;
      }
    }

    const float mo = __shfl_xor(m, 32);
    const float lo = __shfl_xor(l, 32);
    f4_ ao;
    ao.x = __shfl_xor(acc.x, 32); ao.y = __shfl_xor(acc.y, 32);
    ao.z = __shfl_xor(acc.z, 32); ao.w = __shfl_xor(acc.w, 32);
    const float mm = fmaxf(m, mo);
    const float w0 = __expf(m - mm), w1 = __expf(mo - mm);
    const float lm = l * w0 + lo * w1;
    f4_ am = acc * w0 + ao * w1;

    if (half == 0) {
      *(f4_*)&sacc[w][l32 * 4] = am;
      if (l32 == 0) { sm[w] = mm; sl[w] = lm; }
    }
    __syncthreads();

    if (threadIdx.x < 32) {
      const int t = threadIdx.x;
      float mg = NEG_BIG_;
#pragma unroll
      for (int u = 0; u < 4; ++u)
        if (sl[u] > 0.f) mg = fmaxf(mg, sm[u]);
      float ls = 0.f;
      f4_ o = (f4_)0.f;
#pragma unroll
      for (int u = 0; u < 4; ++u)
        if (sl[u] > 0.f) {
          const float wu = __expf(sm[u] - mg);
          ls += sl[u] * wu;
          o  += wu * ld4(&sacc[u][t * 4]);
        }
      float* pb = part + (size_t)bid * PSTR_;
      *(f4_*)(pb + 4 + t * 4) = o;
      if (t == 0) { pb[0] = (ls > 0.f) ? mg : NEG_BIG_; pb[1] = ls; }
    }
    __syncthreads();   // keep sacc/sm/sl reuse safe across reps
  }
}

extern "C" void kernel_launch(void* const* d_in, const int* in_sizes, int n_in,
                              void* d_out, int out_size, void* d_ws, size_t ws_size,
                              hipStream_t stream) {
  const float* x  = (const float*)d_in[0];
  const float* ck = (const float*)d_in[1];
  const float* cv = (const float*)d_in[2];
  const float* wq = (const float*)d_in[3];
  const float* wk = (const float*)d_in[4];
  const float* wv = (const float*)d_in[5];
  const float* wo = (const float*)d_in[6];
  const int* pos  = (const int*)d_in[7];
  float* out = (float*)d_out;
  float* ws  = (float*)d_ws;

  float* qkv     = ws;                                   // 98304 floats
  float* part    = ws + 3 * B_ * HID_;                   // 135168 floats
  float* attnout = part + NPAIR_ * NSPLIT_ * PSTR_;      // 32768 floats
  float* probe1  = attnout + B_ * HID_;                  // qkv-size probe out
  float* probe2  = probe1 + 3 * B_ * HID_;               // part-size probe out
  float* probe3  = probe2 + NPAIR_ * NSPLIT_ * PSTR_;    // wo-size probe out

  // ---- real pipeline (round-5 config) ----
  gemv_rows<<<3 * 512, 256, 0, stream>>>(wq, wk, wv, x, qkv);
  attn_partial<<<NPAIR_ * NSPLIT_, 256, 0, stream>>>(qkv, ck, cv, pos, part);
  attn_combine<<<NPAIR_, 128, 0, stream>>>(part, attnout);
  gemv_rows<<<512, 256, 0, stream>>>(wo, wo, wo, attnout, out);

  // ---- measurement probes (dead outputs; sized to exceed fill dur) ----
  attn_probe<<<NPAIR_ * NSPLIT_, 256, 0, stream>>>(qkv, ck, cv, pos, probe2, 5);
  gemv_probe<<<3 * 512, 256, 0, stream>>>(wq, wk, wv, x, probe1, 16, 512);
  gemv_probe<<<512, 256, 0, stream>>>(wo, wo, wo, attnout, probe3, 32, 512);
}

// Round 9
// 235.515 us; speedup vs baseline: 10.3926x; 10.3926x over previous
//
#include <hip/hip_runtime.h>
#include <cmath>
#include <cstdint>

// Problem constants (fixed by reference file)
#define B_     8
#define NH_    32
#define HD_    128
#define HID_   4096
#define MAXS_  4096
#define NPAIR_ (B_ * NH_)          // 256 (b,h) pairs
#define NSPLIT_ 4                  // key-splits per pair
#define PSTR_  132                 // partial stride: m, l, pad, pad, acc[128]
#define NEG_BIG_ (-1e30f)

typedef float f4_ __attribute__((ext_vector_type(4)));

__device__ __forceinline__ f4_ ntload4(const float* p) {
  return __builtin_nontemporal_load((const f4_*)p);
}
__device__ __forceinline__ f4_ ld4(const float* p) {
  return *(const f4_*)p;
}
__device__ __forceinline__ float dot4(f4_ a, f4_ b) {
  f4_ m = a * b;
  return m.x + m.y + m.z + m.w;
}

// Async global->LDS stage of 16 B/lane (1 KB per wave-instruction).
// LDS dest is wave-uniform base + lane*16 (m104/m173 semantics); src is
// per-lane. ldsoff is a raw byte offset into the kernel's dynamic LDS
// (which starts at 0 when the kernel has no static __shared__).
__device__ __forceinline__ void stage_row16(const float* gsrc, unsigned ldsoff) {
  __builtin_amdgcn_global_load_lds(
      (__attribute__((address_space(1))) void*)(uintptr_t)gsrc,
      (__attribute__((address_space(3))) void*)ldsoff,
      16, 0, 0);
}

// GEMV with VGPR-free deep weight pipeline (m97-style LDS double buffer).
// Block = 256 thr (4 waves) owns TR rows, full K=4096 in 16 slices of 256.
// Wave w owns rows [w*RW, w*RW+RW). Per slice: issue async stage of next
// slice (RW x 1KB per wave, no VGPRs held), compute current slice from LDS
// (RW x ds_read_b128) x 8 batches of x (L2-hot), barrier.
// Weights NORMAL loads -> L3-resident across graph replays (KV stream is nt
// and cannot evict them; round5/6 A/B = ~32 us).
template<int TR>
__global__ __launch_bounds__(256) void gemv_lds(
    const float* __restrict__ W0, const float* __restrict__ W1,
    const float* __restrict__ W2, const float* __restrict__ x,
    float* __restrict__ out, int nb_per_mat)
{
  extern __shared__ float dyn[];          // [2][TR][256] floats
  constexpr int RW = TR / 4;              // rows per wave

  const int bid = blockIdx.x;
  const int m   = bid / nb_per_mat;       // matrix index (0..2)
  const int rb  = (bid % nb_per_mat) * TR;
  const float* __restrict__ W = (m == 0) ? W0 : ((m == 1) ? W1 : W2);
  float* o = out + m * (B_ * HID_);

  const int wib  = threadIdx.x >> 6;
  const int lane = threadIdx.x & 63;
  const int r0   = rb + wib * RW;

  float acc[RW][8];
#pragma unroll
  for (int r = 0; r < RW; ++r)
#pragma unroll
    for (int b = 0; b < 8; ++b) acc[r][b] = 0.f;

  // stage(buf, u): wave wib stages its RW rows' slice u into buffer buf
#define STAGE_(buf, u)                                                        \
  {                                                                           \
    _Pragma("unroll")                                                         \
    for (int rr = 0; rr < RW; ++rr) {                                         \
      const int row = wib * RW + rr;                                          \
      stage_row16(W + (size_t)(rb + row) * HID_ + (u) * 256 + lane * 4,       \
                  (unsigned)(((buf) * TR + row) * 1024));                     \
    }                                                                         \
  }

  STAGE_(0, 0);
  __syncthreads();

  int cur = 0;
  for (int u = 0; u < 16; ++u) {
    if (u + 1 < 16) STAGE_(cur ^ 1, u + 1);

    const int j = u * 256;
    f4_ xv[8];
#pragma unroll
    for (int b = 0; b < 8; ++b) xv[b] = ld4(x + b * HID_ + j + lane * 4);
    f4_ wv[RW];
#pragma unroll
    for (int rr = 0; rr < RW; ++rr)
      wv[rr] = ld4(&dyn[(cur * TR + wib * RW + rr) * 256 + lane * 4]);
#pragma unroll
    for (int rr = 0; rr < RW; ++rr)
#pragma unroll
      for (int b = 0; b < 8; ++b) acc[rr][b] += dot4(wv[rr], xv[b]);

    __syncthreads();     // waits next-slice staging (vmcnt drain) + reuse safety
    cur ^= 1;
  }
#undef STAGE_

  // butterfly reduce each partial across the 64-lane wave
#pragma unroll
  for (int r = 0; r < RW; ++r)
#pragma unroll
    for (int b = 0; b < 8; ++b) {
      float v = acc[r][b];
#pragma unroll
      for (int off = 32; off; off >>= 1) v += __shfl_xor(v, off);
      acc[r][b] = v;
    }

  if (lane == 0) {
#pragma unroll
    for (int r = 0; r < RW; ++r)
#pragma unroll
      for (int b = 0; b < 8; ++b)
        o[(size_t)b * HID_ + r0 + r] = acc[r][b];
  }
}

// Flash-decoding partials: 4 blocks (256 thr = 4 waves) per (b,h) pair.
// K/V rows nt (stream-once; must not evict L3-resident weights).
__global__ __launch_bounds__(256, 4) void attn_partial(
    const float* __restrict__ qkv, const float* __restrict__ ck,
    const float* __restrict__ cv, const int* __restrict__ ppos,
    float* __restrict__ part)
{
  __shared__ float sm[4], sl[4];
  __shared__ float sacc[4][HD_];

  const int pos  = *ppos;
  const int bid  = blockIdx.x;
  const int pair = bid >> 2;
  const int s    = bid & (NSPLIT_ - 1);
  const int b    = pair >> 5;
  const int h    = pair & (NH_ - 1);
  const int w    = threadIdx.x >> 6;
  const int lane = threadIdx.x & 63;
  const int half = lane >> 5, l32 = lane & 31;
  const int k0   = s * 512 + w * 128;

  float m = NEG_BIG_, l = 0.f;
  f4_ acc = (f4_)0.f;

  if (k0 <= pos) {
    const float scale = 0.08838834764831845f;   // 1/sqrt(128)
    f4_ q4 = ld4(qkv + b * HID_ + h * HD_ + l32 * 4) * scale;
    const float* kfresh = qkv + B_ * HID_     + b * HID_ + h * HD_;
    const float* vfresh = qkv + 2 * B_ * HID_ + b * HID_ + h * HD_;
    const float* ckh = ck + ((size_t)(b * NH_ + h)) * MAXS_ * HD_;
    const float* cvh = cv + ((size_t)(b * NH_ + h)) * MAXS_ * HD_;

    for (int c = 0; c < 8; ++c) {
      const int kbase = k0 + c * 16;
      f4_ k4[8], v4[8];
#pragma unroll
      for (int j = 0; j < 8; ++j) {
        const int ki = kbase + 2 * j + half;
        const float* kp = (ki == pos) ? kfresh : (ckh + (size_t)ki * HD_);
        const float* vp = (ki == pos) ? vfresh : (cvh + (size_t)ki * HD_);
        k4[j] = ntload4(kp + l32 * 4);
        v4[j] = ntload4(vp + l32 * 4);
      }

      float sc[8];
#pragma unroll
      for (int j = 0; j < 8; ++j) sc[j] = dot4(q4, k4[j]);

#pragma unroll
      for (int off = 16; off >= 1; off >>= 1)
#pragma unroll
        for (int j = 0; j < 8; ++j) sc[j] += __shfl_xor(sc[j], off);

#pragma unroll
      for (int j = 0; j < 8; ++j) {
        const int ki = kbase + 2 * j + half;
        if (ki > pos) sc[j] = -INFINITY;
      }

      const float cm = fmaxf(fmaxf(fmaxf(sc[0], sc[1]), fmaxf(sc[2], sc[3])),
                             fmaxf(fmaxf(sc[4], sc[5]), fmaxf(sc[6], sc[7])));
      const float mn   = fmaxf(m, cm);
      const float corr = __expf(m - mn);
      float p[8], ps = 0.f;
#pragma unroll
      for (int j = 0; j < 8; ++j) { p[j] = __expf(sc[j] - mn); ps += p[j]; }
      l = l * corr + ps;
      acc *= corr;
#pragma unroll
      for (int j = 0; j < 8; ++j) acc += p[j] * v4[j];
      m = mn;
    }
  }

  const float mo = __shfl_xor(m, 32);
  const float lo = __shfl_xor(l, 32);
  f4_ ao;
  ao.x = __shfl_xor(acc.x, 32); ao.y = __shfl_xor(acc.y, 32);
  ao.z = __shfl_xor(acc.z, 32); ao.w = __shfl_xor(acc.w, 32);
  const float mm = fmaxf(m, mo);
  const float w0 = __expf(m - mm), w1 = __expf(mo - mm);
  const float lm = l * w0 + lo * w1;
  f4_ am = acc * w0 + ao * w1;

  if (half == 0) {
    *(f4_*)&sacc[w][l32 * 4] = am;
    if (l32 == 0) { sm[w] = mm; sl[w] = lm; }
  }
  __syncthreads();

  if (threadIdx.x < 32) {
    const int t = threadIdx.x;
    float mg = NEG_BIG_;
#pragma unroll
    for (int u = 0; u < 4; ++u)
      if (sl[u] > 0.f) mg = fmaxf(mg, sm[u]);
    float ls = 0.f;
    f4_ o = (f4_)0.f;
#pragma unroll
    for (int u = 0; u < 4; ++u)
      if (sl[u] > 0.f) {
        const float wu = __expf(sm[u] - mg);
        ls += sl[u] * wu;
        o  += wu * ld4(&sacc[u][t * 4]);
      }
    float* pb = part + (size_t)bid * PSTR_;
    *(f4_*)(pb + 4 + t * 4) = o;
    if (t == 0) { pb[0] = (ls > 0.f) ? mg : NEG_BIG_; pb[1] = ls; }
  }
}

// Merge the 4 split partials per (b,h) into attn output [b][h*128+d].
__global__ __launch_bounds__(128) void attn_combine(
    const float* __restrict__ part, float* __restrict__ attnout)
{
  const int pair = blockIdx.x;
  const int d    = threadIdx.x;
  const float* pb = part + (size_t)pair * NSPLIT_ * PSTR_;

  float mg = NEG_BIG_;
#pragma unroll
  for (int u = 0; u < NSPLIT_; ++u) {
    const float lu = pb[u * PSTR_ + 1];
    if (lu > 0.f) mg = fmaxf(mg, pb[u * PSTR_]);
  }
  float ls = 0.f, o = 0.f;
#pragma unroll
  for (int u = 0; u < NSPLIT_; ++u) {
    const float lu = pb[u * PSTR_ + 1];
    if (lu > 0.f) {
      const float wu = __expf(pb[u * PSTR_] - mg);
      ls += lu * wu;
      o  += wu * pb[u * PSTR_ + 4 + d];
    }
  }
  attnout[pair * HD_ + d] = o / ls;
}

extern "C" void kernel_launch(void* const* d_in, const int* in_sizes, int n_in,
                              void* d_out, int out_size, void* d_ws, size_t ws_size,
                              hipStream_t stream) {
  const float* x  = (const float*)d_in[0];
  const float* ck = (const float*)d_in[1];
  const float* cv = (const float*)d_in[2];
  const float* wq = (const float*)d_in[3];
  const float* wk = (const float*)d_in[4];
  const float* wv = (const float*)d_in[5];
  const float* wo = (const float*)d_in[6];
  const int* pos  = (const int*)d_in[7];
  float* out = (float*)d_out;
  float* ws  = (float*)d_ws;

  float* qkv     = ws;                                   // 3*8*4096 floats
  float* part    = ws + 3 * B_ * HID_;                   // 1024 * 132 floats
  float* attnout = part + NPAIR_ * NSPLIT_ * PSTR_;      // 8*4096 floats

  // QKV: 3 x 256 blocks of 16 rows; LDS = 2*16*1024 B = 32 KB
  gemv_lds<16><<<3 * 256, 256, 32768, stream>>>(wq, wk, wv, x, qkv, 256);
  attn_partial<<<NPAIR_ * NSPLIT_, 256, 0, stream>>>(qkv, ck, cv, pos, part);
  attn_combine<<<NPAIR_, 128, 0, stream>>>(part, attnout);
  // wo: 512 blocks of 8 rows; LDS = 2*8*1024 B = 16 KB
  gemv_lds<8><<<512, 256, 16384, stream>>>(wo, wo, wo, attnout, out, 512);
}